// Round 19
// baseline (152.198 us; speedup 1.0000x reference)
//
#include <hip/hip_runtime.h>

// GraphAttentionLayer: B=1, N=4096, F=256, H=8, U=64
//
// e_src cancels in softmax over j =>
//   out[i, u*8+h] = relu( (A @ (w*h))[i, h*64+u] / (A @ w)[i, h] ),  w = exp(e_dst)
// => ONE dense GEMM  C = A(4096x4096) x G(4096x544), G = [w*h (512) | w (8) | 0 (24)]
//
// R21: k_gemm occupancy 2x via in-block k-split. Budget fog resolved over
// R11-R20: fixed overhead ~44us; controllable = k_gemm 44 + k_hg ~45 + k_out 8
// + k_pre 5. R18's law: k_gemm throughput scales LINEARLY with wave count
// (256 blk = 92us = 2x the 512-blk 44us, same per-wave shape). VGPR=64 ->
// HW supports 8 waves/SIMD; the GRID (2 blk/CU) is the cap.
//  k_gemm: grid 1024 = 128 strips x 4 nq x 2 z (4 blk/CU = 32 waves/CU).
//  Block = 32 rows x 4 n-tiles; 8 waves = (wq n-tile) x (kq chunk-half).
//  Per ds-iter: 4 indep B-loads + 4 A ds_reads + 4 MFMA (proven shape),
//  2 ds-iters/chunk. Num combined across kq in LDS (R19-verified epilogue);
//  den nq==0 round-robin. A staging/swizzle/XCD-z-pinning/BK=256 unchanged.
//  k_pre/k_hg/k_out: R20-frozen.
//
// Gtp layout (HW-verified R4): tile (tk=k>>4, nt=n>>5), id=tk*17+nt, 1024 B:
//   u16[ id*512 + ((n&31) + 32*((k&15)>>3))*8 + (k&7) ]
// A/B MFMA frag (HW-verified R11): data[lane*8+i] = M[row=lane&31][k=(lane>>5)*8+i]
//
// ws: P 2 slabs (17,039,360 B; Xp-hi/lo alias first 4 MB) | Gtp @17039360
//     (4,456,448 B) | Wph @21495808 | Wpl @21757952. Total 22,020,096 B.

typedef unsigned short u16;
typedef unsigned int   u32;
typedef __attribute__((ext_vector_type(8)))  short  short8;    // 8 bf16 (4 VGPR)
typedef __attribute__((ext_vector_type(16))) float  floatx16;  // 32x32 MFMA acc
typedef __attribute__((ext_vector_type(8)))  unsigned short u16x8;
typedef __attribute__((ext_vector_type(4)))  unsigned short u16x4;

__device__ __forceinline__ u16 f2bf(float x) {
  u32 u = __float_as_uint(x);
  u += 0x7fffu + ((u >> 16) & 1u);   // RNE
  return (u16)(u >> 16);
}
__device__ __forceinline__ float bf2f(u16 h) {
  return __uint_as_float((u32)h << 16);
}

// ---------------------------------------------------------------------------
// Kernel 0: X,W fp32 -> hi/lo bf16 in MFMA-frag tile layout (R11-verified).
// ---------------------------------------------------------------------------
__global__ __launch_bounds__(256) void k_pre(const float* __restrict__ X,
                                             const float* __restrict__ W,
                                             u16* __restrict__ Xph, u16* __restrict__ Xpl,
                                             u16* __restrict__ Wph, u16* __restrict__ Wpl) {
  const int b = blockIdx.x, t = threadIdx.x;
  float xv[8];
  u16* dh; u16* dl; size_t doff;
  if (b < 512) {
    int tid  = b * 256 + t;
    int tile = tid >> 6, lane = tid & 63;
    int j = (tile >> 4) * 32 + (lane & 31);
    int k = (tile & 15) * 16 + (lane >> 5) * 8;
    const float* xp = X + (size_t)j * 256 + k;
    float4 v0 = *(const float4*)xp;
    float4 v1 = *(const float4*)(xp + 4);
    xv[0]=v0.x; xv[1]=v0.y; xv[2]=v0.z; xv[3]=v0.w;
    xv[4]=v1.x; xv[5]=v1.y; xv[6]=v1.z; xv[7]=v1.w;
    dh = Xph; dl = Xpl; doff = (size_t)tile * 512 + lane * 8;
  } else {
    int tid  = (b - 512) * 256 + t;
    int tile = tid >> 6, lane = tid & 63;
    int c = (tile >> 4) * 32 + (lane & 31);
    int k = (tile & 15) * 16 + (lane >> 5) * 8;
#pragma unroll
    for (int i = 0; i < 8; ++i) xv[i] = W[(size_t)(k + i) * 512 + c];
    dh = Wph; dl = Wpl; doff = (size_t)tile * 512 + lane * 8;
  }
  u16x8 hi, lo;
#pragma unroll
  for (int i = 0; i < 8; ++i) {
    u16 h = f2bf(xv[i]);
    hi[i] = h;
    lo[i] = f2bf(xv[i] - bf2f(h));
  }
  *(u16x8*)(dh + doff) = hi;
  *(u16x8*)(dl + doff) = lo;
}

// ---------------------------------------------------------------------------
// Kernel 1: h = X@W via split-bf16 3-pass MFMA from pre-tiled fragments.
// (R20-frozen: 8 waves = (wq n-tile) x (ks K-half), pure loads + MFMA.)
// ---------------------------------------------------------------------------
__global__ __launch_bounds__(512, 4) void k_hg(const u16* __restrict__ Xph,
                                               const u16* __restrict__ Xpl,
                                               const u16* __restrict__ Wph,
                                               const u16* __restrict__ Wpl,
                                               const float* __restrict__ av,
                                               u16* __restrict__ Gtp) {
  __shared__ float hbuf[4][64][17];   // partial-h exchange, pad 17 (17.4 KB)
  __shared__ float eL[64];            // [j_local*2 + head_local]
  __shared__ float w8L[64];
  const int t    = threadIdx.x;
  const int bx   = blockIdx.x;         // m-tile (32 j)
  const int y    = blockIdx.y;         // heads 2y, 2y+1
  const int j0   = bx * 32;
  const int wn   = t >> 6, lane = t & 63;
  const int ml   = lane & 31, kh = lane >> 5;
  const int wq   = wn & 3;             // n-tile slot
  const int ks   = wn >> 2;            // K-half
  const int ct   = y * 4 + wq;
  const int c    = ct * 32 + ml;       // global col (0..511)
  const int hl   = wq >> 1;            // head_local 0/1

  if (t < 64) eL[t] = 0.f;
  __syncthreads();

  floatx16 a0, a1;
#pragma unroll
  for (int r = 0; r < 16; ++r) { a0[r] = 0.f; a1[r] = 0.f; }

  const u16* xh = Xph + (size_t)(bx * 16 + ks * 8) * 512 + lane * 8;
  const u16* xl = Xpl + (size_t)(bx * 16 + ks * 8) * 512 + lane * 8;
  const u16* wh = Wph + (size_t)(ct * 16 + ks * 8) * 512 + lane * 8;
  const u16* wl = Wpl + (size_t)(ct * 16 + ks * 8) * 512 + lane * 8;

#pragma unroll
  for (int kp = 0; kp < 4; ++kp) {     // local kt = 2kp, 2kp+1
    short8 fxh0 = *(const short8*)(xh + (size_t)(2 * kp) * 512);
    short8 fxl0 = *(const short8*)(xl + (size_t)(2 * kp) * 512);
    short8 fwh0 = *(const short8*)(wh + (size_t)(2 * kp) * 512);
    short8 fwl0 = *(const short8*)(wl + (size_t)(2 * kp) * 512);
    short8 fxh1 = *(const short8*)(xh + (size_t)(2 * kp + 1) * 512);
    short8 fxl1 = *(const short8*)(xl + (size_t)(2 * kp + 1) * 512);
    short8 fwh1 = *(const short8*)(wh + (size_t)(2 * kp + 1) * 512);
    short8 fwl1 = *(const short8*)(wl + (size_t)(2 * kp + 1) * 512);
    a0 = __builtin_amdgcn_mfma_f32_32x32x16_bf16(fxh0, fwh0, a0, 0, 0, 0);
    a1 = __builtin_amdgcn_mfma_f32_32x32x16_bf16(fxh1, fwh1, a1, 0, 0, 0);
    a0 = __builtin_amdgcn_mfma_f32_32x32x16_bf16(fxh0, fwl0, a0, 0, 0, 0);
    a1 = __builtin_amdgcn_mfma_f32_32x32x16_bf16(fxh1, fwl1, a1, 0, 0, 0);
    a0 = __builtin_amdgcn_mfma_f32_32x32x16_bf16(fxl0, fwh0, a0, 0, 0, 0);
    a1 = __builtin_amdgcn_mfma_f32_32x32x16_bf16(fxl1, fwh1, a1, 0, 0, 0);
  }
  floatx16 hacc;
#pragma unroll
  for (int r = 0; r < 16; ++r) hacc[r] = a0[r] + a1[r];

  // combine K-halves: ks=1 deposits, ks=0 adds (R14-verified)
  if (ks == 1) {
#pragma unroll
    for (int r = 0; r < 16; ++r) hbuf[wq][lane][r] = hacc[r];
  }
  __syncthreads();
  if (ks == 0) {
#pragma unroll
    for (int r = 0; r < 16; ++r) hacc[r] += hbuf[wq][lane][r];

    const float ad = av[64 + (c & 63)];
    float p[16];
#pragma unroll
    for (int r = 0; r < 16; ++r) p[r] = hacc[r] * ad;
#pragma unroll
    for (int m = 1; m <= 16; m <<= 1)
#pragma unroll
      for (int r = 0; r < 16; ++r) p[r] += __shfl_xor(p[r], m);
    if (ml == 0) {
#pragma unroll
      for (int r = 0; r < 16; ++r) {
        int jl = (r & 3) + 8 * (r >> 2) + 4 * kh;
        atomicAdd(&eL[jl * 2 + hl], p[r]);
      }
    }
  }
  __syncthreads();
  if (t < 64) {
    float e = fminf(30.f, fmaxf(-30.f, eL[t]));
    w8L[t] = __expf(e);
  }
  __syncthreads();

  if (ks == 0) {
#pragma unroll
    for (int r = 0; r < 16; ++r) {
      int jl = (r & 3) + 8 * (r >> 2) + 4 * kh;
      int j  = j0 + jl;
      float g = hacc[r] * w8L[jl * 2 + hl];
      Gtp[(size_t)((j >> 4) * 17 + ct) * 512 + ((c & 31) + 32 * ((j & 15) >> 3)) * 8 + (j & 7)] =
          f2bf(g);
    }
  }
  if (t < 64) {
    int jj = t >> 1, lh2 = t & 1, h = 2 * y + lh2, j = j0 + jj;
    Gtp[(size_t)((j >> 4) * 17 + 16) * 512 + (h + 32 * ((jj & 15) >> 3)) * 8 + (jj & 7)] =
        f2bf(w8L[jj * 2 + lh2]);
  }
  if (y == 3 && t < 96) {
    int tk2 = t / 48, r = t - tk2 * 48;
    int slot = (r < 24) ? (8 + r) : (16 + r);
    u16x8 z = {0, 0, 0, 0, 0, 0, 0, 0};
    *(u16x8*)(Gtp + (size_t)(((j0 >> 4) + tk2) * 17 + 16) * 512 + slot * 8) = z;
  }
}

// ---------------------------------------------------------------------------
// Kernel 2: Pz = A(fp32,{0,1}) x G^T via 32x32x16 bf16 MFMA, PLAIN stores.
// R21: grid 1024 = 128 strips x 4 nq x 2 z -> 4 blk/CU = 32 waves/CU.
// Block = 32 rows x 4 n-tiles; 8 waves = (wq n-tile) x (kq chunk-half).
// Per ds-iter: 4 indep B-loads + 4 A ds_reads + 4 MFMA; 2 ds-iters/chunk.
// Num combined across kq in LDS (R19-verified); den nq==0 round-robin
// (wave w -> k-tiles {2w,2w+1}/chunk) + wave reduce. Z=2 XCD-pinned.
// ---------------------------------------------------------------------------
__global__ __launch_bounds__(512, 4) void k_gemm(const float* __restrict__ A,
                                                 const u16* __restrict__ Gtp,
                                                 float* __restrict__ P) {
  __shared__ __align__(16) u16 As[2][32 * 256];  // 2 x 16 KB (epilogue reuses all 32 KB)
  const int t    = threadIdx.x;
  const int bid  = blockIdx.x;
  const int xcd  = bid & 7, seq = bid >> 3;      // seq 0..127; HW round-robins bid%8 -> XCD
  const int z    = xcd >> 2;                     // k-slice, constant per XCD
  const int idx  = ((xcd & 3) << 7) + seq;       // 0..511 per z
  const int strip = idx >> 2;                    // 0..127
  const int nq   = idx & 3;                      // n-quarter
  const int i0   = strip * 32;
  const int kt0  = z * 2048;
  const int w    = t >> 6, lane = t & 63;
  const int ml   = lane & 31, kh = lane >> 5;
  const int wq   = w & 3;                        // n-tile slot
  const int kq   = w >> 2;                       // chunk-half (8 k-tiles)
  const int nt   = nq * 4 + wq;                  // this wave's n-tile (0..15)

  floatx16 c0, dn;
#pragma unroll
  for (int r = 0; r < 16; ++r) { c0[r] = 0.f; dn[r] = 0.f; }

  // A staging (unchanged): thread -> row ar (0..31), q-th float4 at k = (t&15)*4 + q*64
  const int ar  = t >> 4;
  const int af  = (t & 15) * 4;
  const float* pa = A + (size_t)(i0 + ar) * 4096 + kt0 + af;
  const int sbase = ar * 256 + (t & 1) * 4;   // + swizzled granule*8
  const int scb   = (t & 15) >> 1;            // granule = q*8 + scb
  const int arx   = ar & 7;

  // A-frag reads: row m = ml, k-tile j <-> granule 2j+kh, physical g^(ml&7)
  const int arow = ml * 256;
  const int mx   = ml & 7;
  const int gb   = kq * 16;                   // wave's granule base

  float4 areg[4];
#pragma unroll
  for (int q = 0; q < 4; ++q) areg[q] = *(const float4*)(pa + q * 64);
#pragma unroll
  for (int q = 0; q < 4; ++q) {
    u16x4 v = {f2bf(areg[q].x), f2bf(areg[q].y), f2bf(areg[q].z), f2bf(areg[q].w)};
    *(u16x4*)(&As[0][sbase + ((q * 8 + scb) ^ arx) * 8]) = v;
  }
  __syncthreads();

  for (int cc = 0; cc < 8; ++cc) {
    const int cb = cc & 1;
    if (cc < 7) {                    // prefetch next chunk early (hidden by compute)
#pragma unroll
      for (int q = 0; q < 4; ++q)
        areg[q] = *(const float4*)(pa + (cc + 1) * 256 + q * 64);
    }
    const int ktb  = (kt0 >> 4) + cc * 16 + kq * 8;  // wave's 8 k-tiles
#pragma unroll
    for (int ds = 0; ds < 2; ++ds) {
      short8 b0 = *(const short8*)(Gtp + (size_t)((ktb + ds * 4 + 0) * 17 + nt) * 512 + lane * 8);
      short8 b1 = *(const short8*)(Gtp + (size_t)((ktb + ds * 4 + 1) * 17 + nt) * 512 + lane * 8);
      short8 b2 = *(const short8*)(Gtp + (size_t)((ktb + ds * 4 + 2) * 17 + nt) * 512 + lane * 8);
      short8 b3 = *(const short8*)(Gtp + (size_t)((ktb + ds * 4 + 3) * 17 + nt) * 512 + lane * 8);
      short8 a0 = *(const short8*)(&As[cb][arow + ((gb + ds * 8 + 0 + kh) ^ mx) * 8]);
      short8 a1 = *(const short8*)(&As[cb][arow + ((gb + ds * 8 + 2 + kh) ^ mx) * 8]);
      short8 a2 = *(const short8*)(&As[cb][arow + ((gb + ds * 8 + 4 + kh) ^ mx) * 8]);
      short8 a3 = *(const short8*)(&As[cb][arow + ((gb + ds * 8 + 6 + kh) ^ mx) * 8]);
      c0 = __builtin_amdgcn_mfma_f32_32x32x16_bf16(a0, b0, c0, 0, 0, 0);
      c0 = __builtin_amdgcn_mfma_f32_32x32x16_bf16(a1, b1, c0, 0, 0, 0);
      c0 = __builtin_amdgcn_mfma_f32_32x32x16_bf16(a2, b2, c0, 0, 0, 0);
      c0 = __builtin_amdgcn_mfma_f32_32x32x16_bf16(a3, b3, c0, 0, 0, 0);
    }
    // den tile 16: wave covers k-tiles {2w, 2w+1} of this chunk (nq==0 only)
    if (nq == 0) {
      const int ktb2 = (kt0 >> 4) + cc * 16;
      short8 e0 = *(const short8*)(Gtp + (size_t)((ktb2 + w * 2) * 17 + 16) * 512 + lane * 8);
      short8 e1 = *(const short8*)(Gtp + (size_t)((ktb2 + w * 2 + 1) * 17 + 16) * 512 + lane * 8);
      short8 a0 = *(const short8*)(&As[cb][arow + ((w * 4 + kh) ^ mx) * 8]);
      short8 a1 = *(const short8*)(&As[cb][arow + ((w * 4 + 2 + kh) ^ mx) * 8]);
      dn = __builtin_amdgcn_mfma_f32_32x32x16_bf16(a0, e0, dn, 0, 0, 0);
      dn = __builtin_amdgcn_mfma_f32_32x32x16_bf16(a1, e1, dn, 0, 0, 0);
    }
    if (cc < 7) {
      __syncthreads();               // readers of other buffer done
#pragma unroll
      for (int q = 0; q < 4; ++q) {
        u16x4 v = {f2bf(areg[q].x), f2bf(areg[q].y), f2bf(areg[q].z), f2bf(areg[q].w)};
        *(u16x4*)(&As[cb ^ 1][sbase + ((q * 8 + scb) ^ arx) * 8]) = v;
      }
      __syncthreads();               // writes visible
    }
  }

  // ---- epilogue: combine num over kq, reduce den over waves, store P ----
  __syncthreads();                   // all As reads done before reuse
  float* hnum = (float*)&As[0][0];          // 4 wq x 64 lanes x 16 = 16 KB
  float* dred = hnum + 4096;                // 8 waves x 32 rows x 8 = 8 KB
  if (kq == 1) {
#pragma unroll
    for (int r = 0; r < 16; ++r) hnum[(wq * 64 + lane) * 16 + r] = c0[r];
  }
  if (nq == 0 && ml < 8) {
#pragma unroll
    for (int r = 0; r < 16; ++r) {
      int row32 = 4 * kh + (r & 3) + 8 * (r >> 2);
      dred[(w * 32 + row32) * 8 + ml] = dn[r];
    }
  }
  __syncthreads();

  float* Pz = P + (size_t)z * (4096 * 520);
  if (kq == 0) {
    const int col0 = nt * 32 + ml;
    // C/D layout: col = lane&31, row = (r&3) + 8*(r>>2) + 4*(lane>>5)
#pragma unroll
    for (int r = 0; r < 16; ++r) {
      int row = i0 + 4 * kh + (r & 3) + 8 * (r >> 2);
      Pz[(size_t)row * 520 + col0] = c0[r] + hnum[(wq * 64 + lane) * 16 + r];
    }
  }
  if (nq == 0 && t < 256) {
    int row = t >> 3, c = t & 7;     // 32 rows x 8 cols
    float s = 0.f;
#pragma unroll
    for (int ww = 0; ww < 8; ++ww) s += dred[(ww * 32 + row) * 8 + c];
    Pz[(size_t)(i0 + row) * 520 + 512 + c] = s;
  }
}

// ---------------------------------------------------------------------------
// Kernel 3: out[i, u*8+h] = relu( SUMz Pz[i][h*64+u] / SUMz Pz[i][512+h] ).
// float4 loads/stores. 2 rows/block, 2048 blocks.
// ---------------------------------------------------------------------------
__global__ __launch_bounds__(256) void k_out(const float* __restrict__ P,
                                             float* __restrict__ out) {
  __shared__ float ps[2][520];
  const size_t SL = (size_t)4096 * 520;
  const int t    = threadIdx.x;
  const int half = t >> 7, lt = t & 127;
  const int i    = blockIdx.x * 2 + half;
  const float* pr = P + (size_t)i * 520;
  {
    float4 v0 = *(const float4*)(pr + lt * 4);
    float4 v1 = *(const float4*)(pr + SL + lt * 4);
    float4 s  = {v0.x + v1.x, v0.y + v1.y, v0.z + v1.z, v0.w + v1.w};
    *(float4*)(&ps[half][lt * 4]) = s;
    if (lt < 8) ps[half][512 + lt] = pr[512 + lt] + pr[SL + 512 + lt];
  }
  __syncthreads();
  {
    float ov[4];
#pragma unroll
    for (int q = 0; q < 4; ++q) {
      int c = lt * 4 + q;             // c = u*8 + hd
      int u = c >> 3, hd = c & 7;
      float o = ps[half][hd * 64 + u] / ps[half][512 + hd];
      ov[q] = fmaxf(o, 0.f);
    }
    *(float4*)(out + (size_t)i * 512 + lt * 4) = *(float4*)ov;
  }
}

extern "C" void kernel_launch(void* const* d_in, const int* in_sizes, int n_in,
                              void* d_out, int out_size, void* d_ws, size_t ws_size,
                              hipStream_t stream) {
  const float* X  = (const float*)d_in[0];
  const float* A  = (const float*)d_in[1];
  const float* W  = (const float*)d_in[2];
  const float* av = (const float*)d_in[3];
  float* out = (float*)d_out;
  char*  ws  = (char*)d_ws;

  float* P   = (float*)ws;                  // 2 slabs x 4096 x 520 fp32
  u16*   Xph = (u16*)ws;                    // aliases P[0:2MB)  (dead before k_gemm)
  u16*   Xpl = (u16*)(ws + 2097152);        // aliases P[2MB:4MB)
  u16*   Gtp = (u16*)(ws + 17039360);       // 256*17 tiles * 1024 B
  u16*   Wph = (u16*)(ws + 21495808);       // 256 tiles * 1024 B
  u16*   Wpl = (u16*)(ws + 21757952);       // 256 tiles * 1024 B

  k_pre<<<576, 256, 0, stream>>>(X, W, Xph, Xpl, Wph, Wpl);
  k_hg<<<dim3(128, 4), 512, 0, stream>>>(Xph, Xpl, Wph, Wpl, av, Gtp);
  k_gemm<<<1024, 512, 0, stream>>>(A, Gtp, P);
  k_out<<<2048, 256, 0, stream>>>(P, out);
}

// Round 20
// 144.478 us; speedup vs baseline: 1.0534x; 1.0534x over previous
//
#include <hip/hip_runtime.h>

// GraphAttentionLayer: B=1, N=4096, F=256, H=8, U=64
//
// e_src cancels in softmax over j =>
//   out[i, u*8+h] = relu( (A @ (w*h))[i, h*64+u] / (A @ w)[i, h] ),  w = exp(e_dst)
// => ONE dense GEMM  C = A(4096x4096) x G(4096x544), G = [w*h (512) | w (8) | 0 (24)]
//
// R22: B rotate-by-one software pipeline in k_gemm. R21 regressed (k-split
// halved per-wave work vs constant staging -> staging-bound; occupancy never
// rose). The 44us config survived 7 perturbations; its bound is EXPOSED
// B-load latency (loads consumed immediately). Rotate: load it+1's B regs
// before consuming it's -> in-flight loads always belong to the next iter;
// pipeline legally crosses chunk barriers (Gtp read-only global). Differs
// from R16: there the 8 loads were consumed by the same iter's MFMAs.
//  k_gemm: R20/R14 structure + B-pipeline. VGPR ~95 < 128. Grid 512, Z=2.
//  k_pre/k_hg/k_out: R20-frozen (144.16us best).
//
// Gtp layout (HW-verified R4): tile (tk=k>>4, nt=n>>5), id=tk*17+nt, 1024 B:
//   u16[ id*512 + ((n&31) + 32*((k&15)>>3))*8 + (k&7) ]
// A/B MFMA frag (HW-verified R11): data[lane*8+i] = M[row=lane&31][k=(lane>>5)*8+i]
//
// ws: P 2 slabs (17,039,360 B; Xp-hi/lo alias first 4 MB) | Gtp @17039360
//     (4,456,448 B) | Wph @21495808 | Wpl @21757952. Total 22,020,096 B.

typedef unsigned short u16;
typedef unsigned int   u32;
typedef __attribute__((ext_vector_type(8)))  short  short8;    // 8 bf16 (4 VGPR)
typedef __attribute__((ext_vector_type(16))) float  floatx16;  // 32x32 MFMA acc
typedef __attribute__((ext_vector_type(8)))  unsigned short u16x8;
typedef __attribute__((ext_vector_type(4)))  unsigned short u16x4;

__device__ __forceinline__ u16 f2bf(float x) {
  u32 u = __float_as_uint(x);
  u += 0x7fffu + ((u >> 16) & 1u);   // RNE
  return (u16)(u >> 16);
}
__device__ __forceinline__ float bf2f(u16 h) {
  return __uint_as_float((u32)h << 16);
}

// ---------------------------------------------------------------------------
// Kernel 0: X,W fp32 -> hi/lo bf16 in MFMA-frag tile layout (R11-verified).
// ---------------------------------------------------------------------------
__global__ __launch_bounds__(256) void k_pre(const float* __restrict__ X,
                                             const float* __restrict__ W,
                                             u16* __restrict__ Xph, u16* __restrict__ Xpl,
                                             u16* __restrict__ Wph, u16* __restrict__ Wpl) {
  const int b = blockIdx.x, t = threadIdx.x;
  float xv[8];
  u16* dh; u16* dl; size_t doff;
  if (b < 512) {
    int tid  = b * 256 + t;
    int tile = tid >> 6, lane = tid & 63;
    int j = (tile >> 4) * 32 + (lane & 31);
    int k = (tile & 15) * 16 + (lane >> 5) * 8;
    const float* xp = X + (size_t)j * 256 + k;
    float4 v0 = *(const float4*)xp;
    float4 v1 = *(const float4*)(xp + 4);
    xv[0]=v0.x; xv[1]=v0.y; xv[2]=v0.z; xv[3]=v0.w;
    xv[4]=v1.x; xv[5]=v1.y; xv[6]=v1.z; xv[7]=v1.w;
    dh = Xph; dl = Xpl; doff = (size_t)tile * 512 + lane * 8;
  } else {
    int tid  = (b - 512) * 256 + t;
    int tile = tid >> 6, lane = tid & 63;
    int c = (tile >> 4) * 32 + (lane & 31);
    int k = (tile & 15) * 16 + (lane >> 5) * 8;
#pragma unroll
    for (int i = 0; i < 8; ++i) xv[i] = W[(size_t)(k + i) * 512 + c];
    dh = Wph; dl = Wpl; doff = (size_t)tile * 512 + lane * 8;
  }
  u16x8 hi, lo;
#pragma unroll
  for (int i = 0; i < 8; ++i) {
    u16 h = f2bf(xv[i]);
    hi[i] = h;
    lo[i] = f2bf(xv[i] - bf2f(h));
  }
  *(u16x8*)(dh + doff) = hi;
  *(u16x8*)(dl + doff) = lo;
}

// ---------------------------------------------------------------------------
// Kernel 1: h = X@W via split-bf16 3-pass MFMA from pre-tiled fragments.
// (R20-frozen: 8 waves = (wq n-tile) x (ks K-half), pure loads + MFMA.)
// ---------------------------------------------------------------------------
__global__ __launch_bounds__(512, 4) void k_hg(const u16* __restrict__ Xph,
                                               const u16* __restrict__ Xpl,
                                               const u16* __restrict__ Wph,
                                               const u16* __restrict__ Wpl,
                                               const float* __restrict__ av,
                                               u16* __restrict__ Gtp) {
  __shared__ float hbuf[4][64][17];   // partial-h exchange, pad 17 (17.4 KB)
  __shared__ float eL[64];            // [j_local*2 + head_local]
  __shared__ float w8L[64];
  const int t    = threadIdx.x;
  const int bx   = blockIdx.x;         // m-tile (32 j)
  const int y    = blockIdx.y;         // heads 2y, 2y+1
  const int j0   = bx * 32;
  const int wn   = t >> 6, lane = t & 63;
  const int ml   = lane & 31, kh = lane >> 5;
  const int wq   = wn & 3;             // n-tile slot
  const int ks   = wn >> 2;            // K-half
  const int ct   = y * 4 + wq;
  const int c    = ct * 32 + ml;       // global col (0..511)
  const int hl   = wq >> 1;            // head_local 0/1

  if (t < 64) eL[t] = 0.f;
  __syncthreads();

  floatx16 a0, a1;
#pragma unroll
  for (int r = 0; r < 16; ++r) { a0[r] = 0.f; a1[r] = 0.f; }

  const u16* xh = Xph + (size_t)(bx * 16 + ks * 8) * 512 + lane * 8;
  const u16* xl = Xpl + (size_t)(bx * 16 + ks * 8) * 512 + lane * 8;
  const u16* wh = Wph + (size_t)(ct * 16 + ks * 8) * 512 + lane * 8;
  const u16* wl = Wpl + (size_t)(ct * 16 + ks * 8) * 512 + lane * 8;

#pragma unroll
  for (int kp = 0; kp < 4; ++kp) {     // local kt = 2kp, 2kp+1
    short8 fxh0 = *(const short8*)(xh + (size_t)(2 * kp) * 512);
    short8 fxl0 = *(const short8*)(xl + (size_t)(2 * kp) * 512);
    short8 fwh0 = *(const short8*)(wh + (size_t)(2 * kp) * 512);
    short8 fwl0 = *(const short8*)(wl + (size_t)(2 * kp) * 512);
    short8 fxh1 = *(const short8*)(xh + (size_t)(2 * kp + 1) * 512);
    short8 fxl1 = *(const short8*)(xl + (size_t)(2 * kp + 1) * 512);
    short8 fwh1 = *(const short8*)(wh + (size_t)(2 * kp + 1) * 512);
    short8 fwl1 = *(const short8*)(wl + (size_t)(2 * kp + 1) * 512);
    a0 = __builtin_amdgcn_mfma_f32_32x32x16_bf16(fxh0, fwh0, a0, 0, 0, 0);
    a1 = __builtin_amdgcn_mfma_f32_32x32x16_bf16(fxh1, fwh1, a1, 0, 0, 0);
    a0 = __builtin_amdgcn_mfma_f32_32x32x16_bf16(fxh0, fwl0, a0, 0, 0, 0);
    a1 = __builtin_amdgcn_mfma_f32_32x32x16_bf16(fxh1, fwl1, a1, 0, 0, 0);
    a0 = __builtin_amdgcn_mfma_f32_32x32x16_bf16(fxl0, fwh0, a0, 0, 0, 0);
    a1 = __builtin_amdgcn_mfma_f32_32x32x16_bf16(fxl1, fwh1, a1, 0, 0, 0);
  }
  floatx16 hacc;
#pragma unroll
  for (int r = 0; r < 16; ++r) hacc[r] = a0[r] + a1[r];

  // combine K-halves: ks=1 deposits, ks=0 adds (R14-verified)
  if (ks == 1) {
#pragma unroll
    for (int r = 0; r < 16; ++r) hbuf[wq][lane][r] = hacc[r];
  }
  __syncthreads();
  if (ks == 0) {
#pragma unroll
    for (int r = 0; r < 16; ++r) hacc[r] += hbuf[wq][lane][r];

    const float ad = av[64 + (c & 63)];
    float p[16];
#pragma unroll
    for (int r = 0; r < 16; ++r) p[r] = hacc[r] * ad;
#pragma unroll
    for (int m = 1; m <= 16; m <<= 1)
#pragma unroll
      for (int r = 0; r < 16; ++r) p[r] += __shfl_xor(p[r], m);
    if (ml == 0) {
#pragma unroll
      for (int r = 0; r < 16; ++r) {
        int jl = (r & 3) + 8 * (r >> 2) + 4 * kh;
        atomicAdd(&eL[jl * 2 + hl], p[r]);
      }
    }
  }
  __syncthreads();
  if (t < 64) {
    float e = fminf(30.f, fmaxf(-30.f, eL[t]));
    w8L[t] = __expf(e);
  }
  __syncthreads();

  if (ks == 0) {
#pragma unroll
    for (int r = 0; r < 16; ++r) {
      int jl = (r & 3) + 8 * (r >> 2) + 4 * kh;
      int j  = j0 + jl;
      float g = hacc[r] * w8L[jl * 2 + hl];
      Gtp[(size_t)((j >> 4) * 17 + ct) * 512 + ((c & 31) + 32 * ((j & 15) >> 3)) * 8 + (j & 7)] =
          f2bf(g);
    }
  }
  if (t < 64) {
    int jj = t >> 1, lh2 = t & 1, h = 2 * y + lh2, j = j0 + jj;
    Gtp[(size_t)((j >> 4) * 17 + 16) * 512 + (h + 32 * ((jj & 15) >> 3)) * 8 + (jj & 7)] =
        f2bf(w8L[jj * 2 + lh2]);
  }
  if (y == 3 && t < 96) {
    int tk2 = t / 48, r = t - tk2 * 48;
    int slot = (r < 24) ? (8 + r) : (16 + r);
    u16x8 z = {0, 0, 0, 0, 0, 0, 0, 0};
    *(u16x8*)(Gtp + (size_t)(((j0 >> 4) + tk2) * 17 + 16) * 512 + slot * 8) = z;
  }
}

// ---------------------------------------------------------------------------
// Kernel 2: Pz = A(fp32,{0,1}) x G^T via 32x32x16 bf16 MFMA, PLAIN stores.
// R22: R14/R20 44us structure + B rotate-by-one pipeline: iteration it's
// MFMAs consume regs loaded LAST iteration; it+1's 4 loads issue first.
// Pipeline crosses chunk barriers (Gtp read-only). BM=32, N-split, Z=2,
// XCD-pinned, launch_bounds(512,4).
// ---------------------------------------------------------------------------
__global__ __launch_bounds__(512, 4) void k_gemm(const float* __restrict__ A,
                                                 const u16* __restrict__ Gtp,
                                                 float* __restrict__ P) {
  __shared__ __align__(16) u16 As[2][32 * 256];  // 2 x 16 KB
  const int t    = threadIdx.x;
  const int bid  = blockIdx.x;
  const int xcd  = bid & 7, seq = bid >> 3;      // HW round-robins blockIdx%8 -> XCD
  const int z    = xcd >> 2;                     // k-slice, constant per XCD
  const int idx  = ((xcd & 3) << 6) + seq;       // 0..255 per z
  const int strip = idx >> 1;                    // 0..127
  const int nh   = idx & 1;                      // n-half
  const int i0   = strip * 32;
  const int kt0  = z * 2048;
  const int w    = t >> 6, lane = t & 63;
  const int ml   = lane & 31, kh = lane >> 5;
  const int nt   = nh * 8 + w;                   // this wave's n-tile

  floatx16 c0, dn;
#pragma unroll
  for (int r = 0; r < 16; ++r) { c0[r] = 0.f; dn[r] = 0.f; }

  // A staging: thread -> row ar (0..31), q-th float4 at k = (t&15)*4 + q*64
  const int ar  = t >> 4;
  const int af  = (t & 15) * 4;
  const float* pa = A + (size_t)(i0 + ar) * 4096 + kt0 + af;
  const int sbase = ar * 256 + (t & 1) * 4;   // + swizzled granule*8
  const int scb   = (t & 15) >> 1;            // granule = q*8 + scb
  const int arx   = ar & 7;

  // A-frag reads: row m = ml, granule g -> physical g^(ml&7); k-tile j <-> granule 2j+kh
  const int arow = ml * 256;
  const int mx   = ml & 7;

  // B address base: k-tile kt -> Gtp + (kt*17 + nt)*512 + lane*8
  const u16* gb = Gtp + (size_t)nt * 512 + (size_t)lane * 8;
  const int kb0 = kt0 >> 4;                   // first k-tile

  float4 areg[4];
#pragma unroll
  for (int q = 0; q < 4; ++q) areg[q] = *(const float4*)(pa + q * 64);
#pragma unroll
  for (int q = 0; q < 4; ++q) {
    u16x4 v = {f2bf(areg[q].x), f2bf(areg[q].y), f2bf(areg[q].z), f2bf(areg[q].w)};
    *(u16x4*)(&As[0][sbase + ((q * 8 + scb) ^ arx) * 8]) = v;
  }

  // B pipeline prologue: load iteration 0's 4 k-tiles (kb0+0..3)
  short8 bc0 = *(const short8*)(gb + (size_t)(kb0 + 0) * 17 * 512);
  short8 bc1 = *(const short8*)(gb + (size_t)(kb0 + 1) * 17 * 512);
  short8 bc2 = *(const short8*)(gb + (size_t)(kb0 + 2) * 17 * 512);
  short8 bc3 = *(const short8*)(gb + (size_t)(kb0 + 3) * 17 * 512);
  __syncthreads();

  for (int cc = 0; cc < 8; ++cc) {
    const int cb = cc & 1;
    if (cc < 7) {                    // prefetch next A chunk early
#pragma unroll
      for (int q = 0; q < 4; ++q)
        areg[q] = *(const float4*)(pa + (cc + 1) * 256 + q * 64);
    }
#pragma unroll
    for (int ds = 0; ds < 4; ++ds) {
      // issue NEXT iteration's B loads first (it = cc*4+ds; next = it+1)
      short8 bn0 = bc0, bn1 = bc1, bn2 = bc2, bn3 = bc3;
      if (cc < 7 || ds < 3) {
        const int nb = kb0 + (cc * 4 + ds + 1) * 4;
        bn0 = *(const short8*)(gb + (size_t)(nb + 0) * 17 * 512);
        bn1 = *(const short8*)(gb + (size_t)(nb + 1) * 17 * 512);
        bn2 = *(const short8*)(gb + (size_t)(nb + 2) * 17 * 512);
        bn3 = *(const short8*)(gb + (size_t)(nb + 3) * 17 * 512);
      }
      // consume CURRENT iteration's B (loaded last iteration)
      short8 a0 = *(const short8*)(&As[cb][arow + ((ds * 8 + 0 + kh) ^ mx) * 8]);
      short8 a1 = *(const short8*)(&As[cb][arow + ((ds * 8 + 2 + kh) ^ mx) * 8]);
      short8 a2 = *(const short8*)(&As[cb][arow + ((ds * 8 + 4 + kh) ^ mx) * 8]);
      short8 a3 = *(const short8*)(&As[cb][arow + ((ds * 8 + 6 + kh) ^ mx) * 8]);
      c0 = __builtin_amdgcn_mfma_f32_32x32x16_bf16(a0, bc0, c0, 0, 0, 0);
      c0 = __builtin_amdgcn_mfma_f32_32x32x16_bf16(a1, bc1, c0, 0, 0, 0);
      c0 = __builtin_amdgcn_mfma_f32_32x32x16_bf16(a2, bc2, c0, 0, 0, 0);
      c0 = __builtin_amdgcn_mfma_f32_32x32x16_bf16(a3, bc3, c0, 0, 0, 0);
      bc0 = bn0; bc1 = bn1; bc2 = bn2; bc3 = bn3;
    }
    // den tile 16: wave covers k-tiles {2w, 2w+1} of this chunk (nh==0 only)
    if (nh == 0) {
      const int ktb = (kt0 >> 4) + cc * 16;
      short8 e0 = *(const short8*)(Gtp + (size_t)((ktb + w * 2) * 17 + 16) * 512 + lane * 8);
      short8 e1 = *(const short8*)(Gtp + (size_t)((ktb + w * 2 + 1) * 17 + 16) * 512 + lane * 8);
      short8 a0 = *(const short8*)(&As[cb][arow + ((w * 4 + kh) ^ mx) * 8]);
      short8 a1 = *(const short8*)(&As[cb][arow + ((w * 4 + 2 + kh) ^ mx) * 8]);
      dn = __builtin_amdgcn_mfma_f32_32x32x16_bf16(a0, e0, dn, 0, 0, 0);
      dn = __builtin_amdgcn_mfma_f32_32x32x16_bf16(a1, e1, dn, 0, 0, 0);
    }
    if (cc < 7) {
      __syncthreads();               // readers of other buffer done
#pragma unroll
      for (int q = 0; q < 4; ++q) {
        u16x4 v = {f2bf(areg[q].x), f2bf(areg[q].y), f2bf(areg[q].z), f2bf(areg[q].w)};
        *(u16x4*)(&As[cb ^ 1][sbase + ((q * 8 + scb) ^ arx) * 8]) = v;
      }
      __syncthreads();               // writes visible
    }
  }

  // ---- epilogue: plain stores to slab z (no atomics) ----
  float* Pz = P + (size_t)z * (4096 * 520);
  const int col0 = nt * 32 + ml;
  // C/D layout: col = lane&31, row = (r&3) + 8*(r>>2) + 4*(lane>>5)
#pragma unroll
  for (int r = 0; r < 16; ++r) {
    int row = i0 + 4 * kh + (r & 3) + 8 * (r >> 2);
    Pz[(size_t)row * 520 + col0] = c0[r];
  }

  // den cols 512..519: reduce dn across the 8 waves via LDS (As[0] free:
  // last read in chunk cc==6, all waves past that barrier).
  if (nh == 0) {
    float* dred = (float*)&As[0][0];   // 8 waves x 32 rows x 8 cols = 8 KB
    if (ml < 8) {
#pragma unroll
      for (int r = 0; r < 16; ++r) {
        int row32 = 4 * kh + (r & 3) + 8 * (r >> 2);
        dred[(w * 32 + row32) * 8 + ml] = dn[r];
      }
    }
    __syncthreads();
    if (t < 256) {
      int row = t >> 3, c = t & 7;   // 32 rows x 8 cols
      float s = 0.f;
#pragma unroll
      for (int ww = 0; ww < 8; ++ww) s += dred[(ww * 32 + row) * 8 + c];
      Pz[(size_t)(i0 + row) * 520 + 512 + c] = s;
    }
  }
}

// ---------------------------------------------------------------------------
// Kernel 3: out[i, u*8+h] = relu( SUMz Pz[i][h*64+u] / SUMz Pz[i][512+h] ).
// float4 loads/stores. 2 rows/block, 2048 blocks.
// ---------------------------------------------------------------------------
__global__ __launch_bounds__(256) void k_out(const float* __restrict__ P,
                                             float* __restrict__ out) {
  __shared__ float ps[2][520];
  const size_t SL = (size_t)4096 * 520;
  const int t    = threadIdx.x;
  const int half = t >> 7, lt = t & 127;
  const int i    = blockIdx.x * 2 + half;
  const float* pr = P + (size_t)i * 520;
  {
    float4 v0 = *(const float4*)(pr + lt * 4);
    float4 v1 = *(const float4*)(pr + SL + lt * 4);
    float4 s  = {v0.x + v1.x, v0.y + v1.y, v0.z + v1.z, v0.w + v1.w};
    *(float4*)(&ps[half][lt * 4]) = s;
    if (lt < 8) ps[half][512 + lt] = pr[512 + lt] + pr[SL + 512 + lt];
  }
  __syncthreads();
  {
    float ov[4];
#pragma unroll
    for (int q = 0; q < 4; ++q) {
      int c = lt * 4 + q;             // c = u*8 + hd
      int u = c >> 3, hd = c & 7;
      float o = ps[half][hd * 64 + u] / ps[half][512 + hd];
      ov[q] = fmaxf(o, 0.f);
    }
    *(float4*)(out + (size_t)i * 512 + lt * 4) = *(float4*)ov;
  }
}

extern "C" void kernel_launch(void* const* d_in, const int* in_sizes, int n_in,
                              void* d_out, int out_size, void* d_ws, size_t ws_size,
                              hipStream_t stream) {
  const float* X  = (const float*)d_in[0];
  const float* A  = (const float*)d_in[1];
  const float* W  = (const float*)d_in[2];
  const float* av = (const float*)d_in[3];
  float* out = (float*)d_out;
  char*  ws  = (char*)d_ws;

  float* P   = (float*)ws;                  // 2 slabs x 4096 x 520 fp32
  u16*   Xph = (u16*)ws;                    // aliases P[0:2MB)  (dead before k_gemm)
  u16*   Xpl = (u16*)(ws + 2097152);        // aliases P[2MB:4MB)
  u16*   Gtp = (u16*)(ws + 17039360);       // 256*17 tiles * 1024 B
  u16*   Wph = (u16*)(ws + 21495808);       // 256 tiles * 1024 B
  u16*   Wpl = (u16*)(ws + 21757952);       // 256 tiles * 1024 B

  k_pre<<<576, 256, 0, stream>>>(X, W, Xph, Xpl, Wph, Wpl);
  k_hg<<<dim3(128, 4), 512, 0, stream>>>(Xph, Xpl, Wph, Wpl, av, Gtp);
  k_gemm<<<512, 512, 0, stream>>>(A, Gtp, P);
  k_out<<<2048, 256, 0, stream>>>(P, out);
}